// Round 2
// baseline (310.115 us; speedup 1.0000x reference)
//
#include <hip/hip_runtime.h>
#include <cstdint>
#include <cstddef>

#define N_NODES 50000
#define N_EDGES 400000
#define E_TOT   (N_EDGES + N_NODES)   // with self-loops
#define D_INF   128
#define C1      256                   // 8 heads * 32
#define HIDC    32
#define OUTC    16
#define NEG_SLOPE 0.2f
#define LOG2E   1.44269504088896340736f

// esrc arena: per-node segment rounded up to 4 ints (aligned int4 id loads)
// + 16 zero pad for over-read. Arena fully zeroed in k_prep so any
// over-read id is 0 (a valid, safe row to gather; masked in the math).
#define ESRC_CAP (E_TOT + 3 * N_NODES + 16)     // 600016

#define ZB_DEG ((N_NODES + 255) / 256)          // 196 blocks: zero deg
#define ZB_ESR ((ESRC_CAP + 255) / 256)         // 2344 blocks: zero esrc arena
#define TB_W   ((2 * D_INF * C1 + 2 * C1 * HIDC + 255) / 256)   // 320: transposes
#define PREP_GRID (ZB_DEG + ZB_ESR + TB_W + 1)  // +1 detect block

#define FILLB ((E_TOT + 255) / 256)             // 1758 fill blocks

typedef __bf16 bf16x8 __attribute__((ext_vector_type(8)));
typedef float  floatx4 __attribute__((ext_vector_type(4)));
typedef float  floatx2 __attribute__((ext_vector_type(2)));
typedef int    intx4  __attribute__((ext_vector_type(4)));
typedef unsigned int uintx4 __attribute__((ext_vector_type(4)));
typedef unsigned int uintx2 __attribute__((ext_vector_type(2)));
typedef unsigned short ushortx8 __attribute__((ext_vector_type(8)));
typedef unsigned short ushortx4 __attribute__((ext_vector_type(4)));

__device__ __forceinline__ unsigned short f2bf(float f) {
  unsigned int u = __builtin_bit_cast(unsigned int, f);
  u += 0x7FFFu + ((u >> 16) & 1u);   // RNE (finite values)
  return (unsigned short)(u >> 16);
}
__device__ __forceinline__ float bf2f(unsigned short u) {
  return __builtin_bit_cast(float, (unsigned int)u << 16);
}
// packed bf16x2 word -> float2 (channels 2j, 2j+1)
__device__ __forceinline__ floatx2 bf2x2(unsigned int u) {
  floatx2 r;
  r.x = __builtin_bit_cast(float, u << 16);
  r.y = __builtin_bit_cast(float, u & 0xffff0000u);
  return r;
}

__device__ __forceinline__ int ld_src(const int* ei, int f, int e) {
  return f ? ei[2 * e] : ei[e];
}
__device__ __forceinline__ int ld_dst(const int* ei, int f, int e) {
  return f ? ei[2 * (N_EDGES + e)] : ei[N_EDGES + e];
}

// ---------- prep: zero deg + zero esrc arena + 4 transposes + detect ----------
__global__ __launch_bounds__(256) void k_prep(
    const int* __restrict__ ei,
    const float* __restrict__ W1l, const float* __restrict__ W1r,
    const float* __restrict__ W2l, const float* __restrict__ W2r,
    unsigned short* __restrict__ W1lT, unsigned short* __restrict__ W1rT,
    unsigned short* __restrict__ W2lT, unsigned short* __restrict__ W2rT,
    int* __restrict__ deg, int* __restrict__ esrc,
    int* __restrict__ total, int* __restrict__ flag) {
  __shared__ int sdet;
  const int bid = blockIdx.x;
  const int tid = threadIdx.x;
  if (bid < ZB_DEG) {
    const int i = bid * 256 + tid;
    if (i < N_NODES) deg[i] = 0;
    if (bid == 0 && tid == 0) *total = 0;
    return;
  }
  if (bid < ZB_DEG + ZB_ESR) {
    const int i = (bid - ZB_DEG) * 256 + tid;
    if (i < ESRC_CAP) esrc[i] = 0;
    return;
  }
  if (bid < ZB_DEG + ZB_ESR + TB_W) {
    int idx = (bid - ZB_DEG - ZB_ESR) * 256 + tid;
    if (idx < D_INF * C1) {                       // W1l: [128][256] -> T
      const int r = idx >> 8, c = idx & 255;
      W1lT[c * D_INF + r] = f2bf(W1l[idx]);
    } else if (idx < 2 * D_INF * C1) {            // W1r
      idx -= D_INF * C1;
      const int r = idx >> 8, c = idx & 255;
      W1rT[c * D_INF + r] = f2bf(W1r[idx]);
    } else if (idx < 2 * D_INF * C1 + C1 * HIDC) { // W2l: [256][32] -> T
      idx -= 2 * D_INF * C1;
      const int r = idx >> 5, c = idx & 31;
      W2lT[c * C1 + r] = f2bf(W2l[idx]);
    } else {                                       // W2r
      idx -= 2 * D_INF * C1 + C1 * HIDC;
      const int r = idx >> 5, c = idx & 31;
      W2rT[c * C1 + r] = f2bf(W2r[idx]);
    }
    return;
  }
  // detect block: int64 edge_index iff all odd words are zero
  if (tid == 0) sdet = 0;
  __syncthreads();
  if (tid < 64) atomicOr(&sdet, ei[2 * tid + 1]);
  __syncthreads();
  if (tid == 0) *flag = (sdet == 0) ? 1 : 0;
}

// ---------- degree count ----------
__global__ void k_deg(const int* __restrict__ ei, const int* __restrict__ flag,
                      int* __restrict__ deg) {
  int e = blockIdx.x * 256 + threadIdx.x;
  if (e < E_TOT) {
    int dst = (e < N_EDGES) ? ld_dst(ei, *flag, e) : (e - N_EDGES);
    if ((unsigned)dst < N_NODES) atomicAdd(&deg[dst], 1);
  }
}

// ---------- segment allocation: per-wave prefix + one atomic per wave ----------
// Segments 4-int aligned; placement order arbitrary (doesn't matter).
__global__ __launch_bounds__(256) void k_alloc(
    const int* __restrict__ deg, int* __restrict__ rowptr,
    int* __restrict__ cursor, int* __restrict__ total) {
  const int i = blockIdx.x * 256 + threadIdx.x;
  const int lane = threadIdx.x & 63;
  const int d  = (i < N_NODES) ? deg[i] : 0;
  const int d4 = (d + 3) & ~3;
  int incl = d4;
#pragma unroll
  for (int off = 1; off < 64; off <<= 1) {
    int t = __shfl_up(incl, off);
    if (lane >= off) incl += t;
  }
  const int wtot = __shfl(incl, 63);
  int wb = 0;
  if (lane == 63) wb = atomicAdd(total, wtot);
  wb = __shfl(wb, 63);
  if (i < N_NODES) {
    const int e = wb + incl - d4;
    rowptr[i] = e;
    cursor[i] = e;
  }
}

// ---------- A-fragment loaders (8 contiguous k-elements -> bf16x8) ----------
__device__ __forceinline__ bf16x8 load8(const unsigned short* p) {
  uintx4 raw = *reinterpret_cast<const uintx4*>(p);
  return __builtin_bit_cast(bf16x8, raw);
}
__device__ __forceinline__ bf16x8 load8(const float* p) {
  floatx4 a = *reinterpret_cast<const floatx4*>(p);
  floatx4 b = *reinterpret_cast<const floatx4*>(p + 4);
  ushortx8 u;
#pragma unroll
  for (int i = 0; i < 4; ++i) { u[i] = f2bf(a[i]); u[4 + i] = f2bf(b[i]); }
  return __builtin_bit_cast(bf16x8, u);
}

// ---------- dual MFMA bf16 GEMM body: C{0,1}[M][NCOLS] = A[M][K] * BT{0,1}^T ----------
template <int K, int NCOLS, typename AT>
__device__ __forceinline__ void gemm_dual_body(
    int unit, int lane, const AT* __restrict__ A,
    const unsigned short* __restrict__ BT0, const unsigned short* __restrict__ BT1,
    unsigned short* __restrict__ C0, unsigned short* __restrict__ C1_, int M) {
  const int lo = lane & 15;   // m for A, n for B, col for C/D
  const int q  = lane >> 4;   // k-chunk quad
  const int r0 = unit * 32;
  if (r0 >= M) return;
  const bool two = (r0 + 16) < M;
  constexpr int KB = K / 32;

  bf16x8 afrag[2][KB];
#pragma unroll
  for (int kb = 0; kb < KB; ++kb)
    afrag[0][kb] = load8(A + (size_t)(r0 + lo) * K + kb * 32 + q * 8);
  if (two) {
#pragma unroll
    for (int kb = 0; kb < KB; ++kb)
      afrag[1][kb] = load8(A + (size_t)(r0 + 16 + lo) * K + kb * 32 + q * 8);
  }

#pragma unroll
  for (int o = 0; o < 2; ++o) {
    const unsigned short* BT = o ? BT1 : BT0;
    unsigned short* C = o ? C1_ : C0;
#pragma unroll
    for (int nt = 0; nt < NCOLS / 16; ++nt) {
      floatx4 acc0 = {0.f, 0.f, 0.f, 0.f};
      floatx4 acc1 = {0.f, 0.f, 0.f, 0.f};
      const unsigned short* bptr = BT + (size_t)(nt * 16 + lo) * K + q * 8;
#pragma unroll
      for (int kb = 0; kb < KB; ++kb) {
        bf16x8 b = load8(bptr + kb * 32);
        acc0 = __builtin_amdgcn_mfma_f32_16x16x32_bf16(afrag[0][kb], b, acc0, 0, 0, 0);
        if (two)
          acc1 = __builtin_amdgcn_mfma_f32_16x16x32_bf16(afrag[1][kb], b, acc1, 0, 0, 0);
      }
      // C/D layout: col = lane&15, row = (lane>>4)*4 + reg   [m89-verified]
#pragma unroll
      for (int r = 0; r < 4; ++r) {
        C[(size_t)(r0 + q * 4 + r) * NCOLS + nt * 16 + lo] = f2bf(acc0[r]);
        if (two)
          C[(size_t)(r0 + 16 + q * 4 + r) * NCOLS + nt * 16 + lo] = f2bf(acc1[r]);
      }
    }
  }
}

// ---------- fused CSR-fill + GEMM1 (disjoint block ranges, overlap pipes) ----------
__global__ __launch_bounds__(256) void k_fill_gemm1(
    const int* __restrict__ ei, const int* __restrict__ flag,
    int* __restrict__ cursor, int* __restrict__ esrc,
    const float* __restrict__ A,
    const unsigned short* __restrict__ BT0, const unsigned short* __restrict__ BT1,
    unsigned short* __restrict__ C0, unsigned short* __restrict__ C1_) {
  if (blockIdx.x < FILLB) {
    const int e = blockIdx.x * 256 + threadIdx.x;
    if (e < E_TOT) {
      int src, dst;
      if (e < N_EDGES) { src = ld_src(ei, *flag, e); dst = ld_dst(ei, *flag, e); }
      else             { src = dst = e - N_EDGES; }
      if ((unsigned)src < N_NODES && (unsigned)dst < N_NODES) {
        int pos = atomicAdd(&cursor[dst], 1);
        esrc[pos] = src;
      }
    }
    return;
  }
  const int wave = threadIdx.x >> 6;
  const int lane = threadIdx.x & 63;
  gemm_dual_body<D_INF, C1, float>((blockIdx.x - FILLB) * 4 + wave, lane,
                                   A, BT0, BT1, C0, C1_, N_NODES);
}

__global__ __launch_bounds__(256) void k_gemm2(
    const unsigned short* __restrict__ A,
    const unsigned short* __restrict__ BT0, const unsigned short* __restrict__ BT1,
    unsigned short* __restrict__ C0, unsigned short* __restrict__ C1_) {
  const int wave = threadIdx.x >> 6;
  const int lane = threadIdx.x & 63;
  gemm_dual_body<C1, HIDC, unsigned short>(blockIdx.x * 4 + wave, lane,
                                           A, BT0, BT1, C0, C1_, N_NODES);
}

// ---------- GAT layer 1 ----------
// One wave per dst; half h = lane>>5 owns alternating edge slots; lane w = lane&31
// owns channels w*8..w*8+7. Batched edge ids (int4 pairs, 4-aligned segments) +
// 8-edges-per-pass gather pipeline, next pass's ids+gathers in flight during
// processing. No softmax max-tracking (scores tiny; fmed3 clamp as insurance).
// h1 may alias xr1 (own-row read-then-write).
__global__ __launch_bounds__(256) void k_gat1(
    const unsigned short* __restrict__ xl1, const unsigned short* __restrict__ xr1,
    const float* __restrict__ att1, const float* __restrict__ b1,
    const int* __restrict__ rowptr, const int* __restrict__ deg,
    const int* __restrict__ esrc, unsigned short* __restrict__ h1) {
  const int wave = threadIdx.x >> 6;
  const int lane = threadIdx.x & 63;
  const int dst = blockIdx.x * 4 + wave;
  if (dst >= N_NODES) return;
  const int h = lane >> 5;
  const int w = lane & 31;
  const int cb = w * 8;
  const unsigned short* __restrict__ xb = xl1 + cb;

  const int beg = rowptr[dst];
  const int n   = deg[dst];
  const int* __restrict__ ep = esrc + beg;

  floatx2 xr2v[4], att2v[4];
  {
    uintx4 r = *reinterpret_cast<const uintx4*>(xr1 + (size_t)dst * C1 + cb);
    floatx4 a0 = *reinterpret_cast<const floatx4*>(att1 + cb);
    floatx4 a1 = *reinterpret_cast<const floatx4*>(att1 + cb + 4);
#pragma unroll
    for (int j = 0; j < 4; ++j) xr2v[j] = bf2x2(r[j]);
    att2v[0] = floatx2{a0.x, a0.y} * LOG2E;
    att2v[1] = floatx2{a0.z, a0.w} * LOG2E;
    att2v[2] = floatx2{a1.x, a1.y} * LOG2E;
    att2v[3] = floatx2{a1.z, a1.w} * LOG2E;
  }

  float l = 0.f;
  floatx2 acc2[4] = {{0.f, 0.f}, {0.f, 0.f}, {0.f, 0.f}, {0.f, 0.f}};

  auto gath = [&](int a, int b) {
    const int s = h ? b : a;
    return *reinterpret_cast<const uintx4*>(xb + (size_t)s * C1);
  };
  auto process = [&](uintx4 cur, float keep) {
    floatx2 xs2[4];
    floatx2 v2 = {0.f, 0.f};
#pragma unroll
    for (int j = 0; j < 4; ++j) {
      xs2[j] = bf2x2(cur[j]);
      floatx2 s2 = xs2[j] + xr2v[j];
      floatx2 e2 = __builtin_elementwise_max(s2, s2 * NEG_SLOPE);   // leaky
      v2 = __builtin_elementwise_fma(e2, att2v[j], v2);
    }
    float v = v2.x + v2.y;
    v += __shfl_xor(v, 1);
    v += __shfl_xor(v, 2);            // 4-lane group = one head
    v = __builtin_amdgcn_fmed3f(v, -100.f, 100.f);
    const float p = __builtin_amdgcn_exp2f(v) * keep;
    l += p;
    const floatx2 p2 = {p, p};
#pragma unroll
    for (int j = 0; j < 4; ++j)
      acc2[j] = __builtin_elementwise_fma(p2, xs2[j], acc2[j]);
  };

  // prologue: pass-0 ids, pass-0 gathers (slot-guarded), pass-1 ids
  intx4 ja = *reinterpret_cast<const intx4*>(ep);
  intx4 jb = *reinterpret_cast<const intx4*>(ep + 4);
  uintx4 g0 = {0u,0u,0u,0u}, g1 = {0u,0u,0u,0u}, g2 = {0u,0u,0u,0u}, g3 = {0u,0u,0u,0u};
  if (h     < n) g0 = gath(ja.x, ja.y);
  if (h + 2 < n) g1 = gath(ja.z, ja.w);
  if (h + 4 < n) g2 = gath(jb.x, jb.y);
  if (h + 6 < n) g3 = gath(jb.z, jb.w);
  intx4 na = *reinterpret_cast<const intx4*>(ep + 8);
  intx4 nb = *reinterpret_cast<const intx4*>(ep + 12);

  int base = 0;
  while (true) {
    const int rem = n - base;         // > 0
    const bool more = rem > 8;
    uintx4 t0, t1, t2, t3;
    intx4 ma, mb;
    if (more) {
      const int remn = rem - 8;
      t0 = t1 = t2 = t3 = uintx4{0u,0u,0u,0u};
      if (h     < remn) t0 = gath(na.x, na.y);
      if (h + 2 < remn) t1 = gath(na.z, na.w);
      if (h + 4 < remn) t2 = gath(nb.x, nb.y);
      if (h + 6 < remn) t3 = gath(nb.z, nb.w);
      ma = *reinterpret_cast<const intx4*>(ep + base + 16);
      mb = *reinterpret_cast<const intx4*>(ep + base + 20);
    }
    if (rem >= 8) {
      process(g0, 1.f); process(g1, 1.f); process(g2, 1.f); process(g3, 1.f);
    } else {
      process(g0, (h     < rem) ? 1.f : 0.f);
      process(g1, (h + 2 < rem) ? 1.f : 0.f);
      process(g2, (h + 4 < rem) ? 1.f : 0.f);
      process(g3, (h + 6 < rem) ? 1.f : 0.f);
    }
    if (!more) break;
    g0 = t0; g1 = t1; g2 = t2; g3 = t3;
    na = ma; nb = mb;
    base += 8;
  }

  // merge the two halves (plain sums; no max bookkeeping)
  l += __shfl_xor(l, 32);
#pragma unroll
  for (int j = 0; j < 4; ++j) {
    acc2[j].x += __shfl_xor(acc2[j].x, 32);
    acc2[j].y += __shfl_xor(acc2[j].y, 32);
  }

  if (h == 0) {
    const float inv = 1.f / fmaxf(l, 1e-16f);
    ushortx8 ob;
#pragma unroll
    for (int j = 0; j < 4; ++j) {
      float z0 = acc2[j].x * inv + b1[cb + 2 * j];
      float z1 = acc2[j].y * inv + b1[cb + 2 * j + 1];
      z0 = z0 > 0.f ? z0 : (__expf(z0) - 1.f);   // ELU
      z1 = z1 > 0.f ? z1 : (__expf(z1) - 1.f);
      ob[2 * j]     = f2bf(z0);
      ob[2 * j + 1] = f2bf(z1);
    }
    *reinterpret_cast<ushortx8*>(h1 + (size_t)dst * C1 + cb) = ob;
  }
}

// ---------- GAT layer 2 (1 head, 32 ch) fused with final linear [32x16] ----------
__global__ __launch_bounds__(256) void k_gat2(
    const unsigned short* __restrict__ xl2, const unsigned short* __restrict__ xr2,
    const float* __restrict__ att2, const float* __restrict__ b2,
    const float* __restrict__ Wlin, const float* __restrict__ blin,
    const int* __restrict__ rowptr, const int* __restrict__ deg,
    const int* __restrict__ esrc, float* __restrict__ out) {
  __shared__ float sh[4][32];
  const int wave = threadIdx.x >> 6;
  const int lane = threadIdx.x & 63;
  const int dst = blockIdx.x * 4 + wave;
  if (dst >= N_NODES) return;
  const int o8 = lane >> 3;   // edge slot (8 edges in flight)
  const int w = lane & 7;     // channel group
  const int cb = w * 4;       // 4 ch = 2 bf16x2 pairs

  floatx2 xr2v[2], att2v[2];
  {
    uintx2 r = *reinterpret_cast<const uintx2*>(xr2 + (size_t)dst * HIDC + cb);
    floatx4 a = *reinterpret_cast<const floatx4*>(att2 + cb);
    xr2v[0] = bf2x2(r[0]);
    xr2v[1] = bf2x2(r[1]);
    att2v[0] = floatx2{a.x, a.y} * LOG2E;
    att2v[1] = floatx2{a.z, a.w} * LOG2E;
  }

  const int beg = rowptr[dst];
  const int n   = deg[dst];
  const int* __restrict__ ep = esrc + beg;

  float l = 0.f;
  floatx2 acc2[2] = {{0.f, 0.f}, {0.f, 0.f}};

  auto process = [&](uintx2 cur) {
    floatx2 xs2[2];
    floatx2 v2 = {0.f, 0.f};
#pragma unroll
    for (int j = 0; j < 2; ++j) {
      xs2[j] = bf2x2(cur[j]);
      floatx2 s2 = xs2[j] + xr2v[j];
      floatx2 e2 = __builtin_elementwise_max(s2, s2 * NEG_SLOPE);
      v2 = __builtin_elementwise_fma(e2, att2v[j], v2);
    }
    float v = v2.x + v2.y;
    v += __shfl_xor(v, 1);
    v += __shfl_xor(v, 2);
    v += __shfl_xor(v, 4);          // 8-lane group = full 32-ch head
    v = __builtin_amdgcn_fmed3f(v, -100.f, 100.f);
    const float p = __builtin_amdgcn_exp2f(v);
    l += p;
    const floatx2 p2 = {p, p};
#pragma unroll
    for (int j = 0; j < 2; ++j)
      acc2[j] = __builtin_elementwise_fma(p2, xs2[j], acc2[j]);
  };

  uintx2 bufa = {0u, 0u}, bufb = {0u, 0u};
  if (o8 < n)
    bufa = *reinterpret_cast<const uintx2*>(xl2 + (size_t)ep[o8] * HIDC + cb);
  if (o8 + 8 < n)
    bufb = *reinterpret_cast<const uintx2*>(xl2 + (size_t)ep[o8 + 8] * HIDC + cb);
  int i = o8;
  while (i < n) {
    process(bufa);
    if (i + 16 < n)
      bufa = *reinterpret_cast<const uintx2*>(xl2 + (size_t)ep[i + 16] * HIDC + cb);
    i += 8;
    if (i >= n) break;
    process(bufb);
    if (i + 16 < n)
      bufb = *reinterpret_cast<const uintx2*>(xl2 + (size_t)ep[i + 16] * HIDC + cb);
    i += 8;
  }

  // merge 8 octets (plain sums)
#pragma unroll
  for (int k = 8; k < 64; k <<= 1) {
    l += __shfl_xor(l, k);
#pragma unroll
    for (int j = 0; j < 2; ++j) {
      acc2[j].x += __shfl_xor(acc2[j].x, k);
      acc2[j].y += __shfl_xor(acc2[j].y, k);
    }
  }

  if (o8 == 0) {
    const float inv = 1.f / fmaxf(l, 1e-16f);
#pragma unroll
    for (int j = 0; j < 2; ++j) {
      float z0 = acc2[j].x * inv + b2[cb + 2 * j];
      float z1 = acc2[j].y * inv + b2[cb + 2 * j + 1];
      z0 = z0 > 0.f ? z0 : (__expf(z0) - 1.f);   // ELU
      z1 = z1 > 0.f ? z1 : (__expf(z1) - 1.f);
      sh[wave][cb + 2 * j]     = z0;
      sh[wave][cb + 2 * j + 1] = z1;
    }
  }
  if (lane < OUTC) {
    float o = blin[lane];
#pragma unroll
    for (int k = 0; k < 32; ++k)
      o = fmaf(sh[wave][k], Wlin[k * OUTC + lane], o);
    out[(size_t)dst * OUTC + lane] = o;
  }
}

static inline int cdiv(int a, int b) { return (a + b - 1) / b; }

extern "C" void kernel_launch(void* const* d_in, const int* in_sizes, int n_in,
                              void* d_out, int out_size, void* d_ws, size_t ws_size,
                              hipStream_t stream) {
  const float* x    = (const float*)d_in[0];
  const int*   ei   = (const int*)d_in[1];
  const float* W1l  = (const float*)d_in[2];
  const float* W1r  = (const float*)d_in[3];
  const float* att1 = (const float*)d_in[4];
  const float* b1   = (const float*)d_in[5];
  const float* W2l  = (const float*)d_in[6];
  const float* W2r  = (const float*)d_in[7];
  const float* att2 = (const float*)d_in[8];
  const float* b2   = (const float*)d_in[9];
  const float* Wlin = (const float*)d_in[10];
  const float* blin = (const float*)d_in[11];
  float* out = (float*)d_out;

  char* w = (char*)d_ws;
  auto alloc = [&](size_t bytes) -> char* {
    char* p = w;
    w += (bytes + 255) & ~(size_t)255;
    return p;
  };
  // region A: xl1 (bf16), later reused for xl2+xr2
  char* regionA = alloc((size_t)N_NODES * C1 * 2);          // 25.6 MB
  unsigned short* xl1 = (unsigned short*)regionA;
  unsigned short* xl2 = (unsigned short*)regionA;                           // 3.2 MB
  unsigned short* xr2 = (unsigned short*)(regionA + (size_t)N_NODES * HIDC * 2 + 256);
  // region B: xr1 aliased with h1 (safe: per-wave own-row read-then-write)
  unsigned short* xr1 = (unsigned short*)alloc((size_t)N_NODES * C1 * 2);   // 25.6 MB
  unsigned short* h1  = xr1;
  unsigned short* W1lT = (unsigned short*)alloc((size_t)D_INF * C1 * 2);
  unsigned short* W1rT = (unsigned short*)alloc((size_t)D_INF * C1 * 2);
  unsigned short* W2lT = (unsigned short*)alloc((size_t)C1 * HIDC * 2);
  unsigned short* W2rT = (unsigned short*)alloc((size_t)C1 * HIDC * 2);
  int* rowptr = (int*)alloc((size_t)N_NODES * 4);
  int* cursor = (int*)alloc((size_t)N_NODES * 4);
  int* deg    = (int*)alloc((size_t)N_NODES * 4);
  int* esrc   = (int*)alloc((size_t)ESRC_CAP * 4);          // 2.4 MB
  int* flag   = (int*)alloc(4);
  int* total  = (int*)alloc(4);

  k_prep<<<PREP_GRID, 256, 0, stream>>>(ei, W1l, W1r, W2l, W2r,
                                        W1lT, W1rT, W2lT, W2rT,
                                        deg, esrc, total, flag);
  k_deg<<<cdiv(E_TOT, 256), 256, 0, stream>>>(ei, flag, deg);
  k_alloc<<<cdiv(N_NODES, 256), 256, 0, stream>>>(deg, rowptr, cursor, total);

  const int gblocks = cdiv(cdiv(N_NODES, 32), 4);   // 391

  // CSR fill + GEMM1 overlapped in one dispatch
  k_fill_gemm1<<<FILLB + gblocks, 256, 0, stream>>>(ei, flag, cursor, esrc,
                                                    x, W1lT, W1rT, xl1, xr1);

  k_gat1<<<cdiv(N_NODES, 4), 256, 0, stream>>>(xl1, xr1, att1, b1,
                                               rowptr, deg, esrc, h1);

  // GEMM2: [50000,256] x ([256,32] x2) -> xl2, xr2
  k_gemm2<<<gblocks, 256, 0, stream>>>(h1, W2lT, W2rT, xl2, xr2);

  k_gat2<<<cdiv(N_NODES, 4), 256, 0, stream>>>(xl2, xr2, att2, b2, Wlin, blin,
                                               rowptr, deg, esrc, out);
}

// Round 3
// 272.787 us; speedup vs baseline: 1.1368x; 1.1368x over previous
//
#include <hip/hip_runtime.h>
#include <cstdint>
#include <cstddef>

#define N_NODES 50000
#define N_EDGES 400000
#define E_TOT   (N_EDGES + N_NODES)   // with self-loops
#define D_INF   128
#define C1      256                   // 8 heads * 32
#define HIDC    32
#define OUTC    16
#define NEG_SLOPE 0.2f
#define LOG2E   1.44269504088896340736f

// esrc arena: per-node segment rounded up to 4 ints (aligned int4 id loads)
// + 16 int pad for benign over-READ of id words (never dereferenced:
// all gathers are exactly guarded by deg[dst]).
#define ESRC_CAP (E_TOT + 3 * N_NODES + 16)     // 600016

#define ZB_DEG ((N_NODES + 255) / 256)          // 196 blocks: zero deg
#define TB_W   ((2 * D_INF * C1 + 2 * C1 * HIDC + 255) / 256)   // 320: transposes
#define PREP_GRID (ZB_DEG + TB_W + 1)           // +1 detect block

#define GB1   ((((N_NODES + 31) / 32) + 3) / 4) // 391 GEMM1 blocks
#define DEGB  ((E_TOT + 255) / 256)             // 1758 deg blocks
#define FILLB ((E_TOT + 255) / 256)

typedef __bf16 bf16x8 __attribute__((ext_vector_type(8)));
typedef float  floatx4 __attribute__((ext_vector_type(4)));
typedef float  floatx2 __attribute__((ext_vector_type(2)));
typedef int    intx4  __attribute__((ext_vector_type(4)));
typedef unsigned int uintx4 __attribute__((ext_vector_type(4)));
typedef unsigned int uintx2 __attribute__((ext_vector_type(2)));
typedef unsigned short ushortx8 __attribute__((ext_vector_type(8)));
typedef unsigned short ushortx4 __attribute__((ext_vector_type(4)));

__device__ __forceinline__ unsigned short f2bf(float f) {
  unsigned int u = __builtin_bit_cast(unsigned int, f);
  u += 0x7FFFu + ((u >> 16) & 1u);   // RNE (finite values)
  return (unsigned short)(u >> 16);
}
__device__ __forceinline__ float bf2f(unsigned short u) {
  return __builtin_bit_cast(float, (unsigned int)u << 16);
}
// packed bf16x2 word -> float2 (channels 2j, 2j+1)
__device__ __forceinline__ floatx2 bf2x2(unsigned int u) {
  floatx2 r;
  r.x = __builtin_bit_cast(float, u << 16);
  r.y = __builtin_bit_cast(float, u & 0xffff0000u);
  return r;
}

__device__ __forceinline__ int ld_src(const int* ei, int f, int e) {
  return f ? ei[2 * e] : ei[e];
}
__device__ __forceinline__ int ld_dst(const int* ei, int f, int e) {
  return f ? ei[2 * (N_EDGES + e)] : ei[N_EDGES + e];
}

// ---------- prep: zero deg + 4 weight transposes + int64-detect ----------
__global__ __launch_bounds__(256) void k_prep(
    const int* __restrict__ ei,
    const float* __restrict__ W1l, const float* __restrict__ W1r,
    const float* __restrict__ W2l, const float* __restrict__ W2r,
    unsigned short* __restrict__ W1lT, unsigned short* __restrict__ W1rT,
    unsigned short* __restrict__ W2lT, unsigned short* __restrict__ W2rT,
    int* __restrict__ deg, int* __restrict__ total, int* __restrict__ flag) {
  __shared__ int sdet;
  const int bid = blockIdx.x;
  const int tid = threadIdx.x;
  if (bid < ZB_DEG) {
    const int i = bid * 256 + tid;
    if (i < N_NODES) deg[i] = 0;
    if (bid == 0 && tid == 0) *total = 0;
    return;
  }
  if (bid < ZB_DEG + TB_W) {
    int idx = (bid - ZB_DEG) * 256 + tid;
    if (idx < D_INF * C1) {                       // W1l: [128][256] -> T
      const int r = idx >> 8, c = idx & 255;
      W1lT[c * D_INF + r] = f2bf(W1l[idx]);
    } else if (idx < 2 * D_INF * C1) {            // W1r
      idx -= D_INF * C1;
      const int r = idx >> 8, c = idx & 255;
      W1rT[c * D_INF + r] = f2bf(W1r[idx]);
    } else if (idx < 2 * D_INF * C1 + C1 * HIDC) { // W2l: [256][32] -> T
      idx -= 2 * D_INF * C1;
      const int r = idx >> 5, c = idx & 31;
      W2lT[c * C1 + r] = f2bf(W2l[idx]);
    } else {                                       // W2r
      idx -= 2 * D_INF * C1 + C1 * HIDC;
      const int r = idx >> 5, c = idx & 31;
      W2rT[c * C1 + r] = f2bf(W2r[idx]);
    }
    return;
  }
  // detect block: int64 edge_index iff all sampled odd words are zero
  if (tid == 0) sdet = 0;
  __syncthreads();
  if (tid < 64) atomicOr(&sdet, ei[2 * tid + 1]);
  __syncthreads();
  if (tid == 0) *flag = (sdet == 0) ? 1 : 0;
}

// ---------- segment allocation: per-wave prefix + one atomic per wave ----------
__global__ __launch_bounds__(256) void k_alloc(
    const int* __restrict__ deg, int* __restrict__ rowptr,
    int* __restrict__ cursor, int* __restrict__ total) {
  const int i = blockIdx.x * 256 + threadIdx.x;
  const int lane = threadIdx.x & 63;
  const int d  = (i < N_NODES) ? deg[i] : 0;
  const int d4 = (d + 3) & ~3;
  int incl = d4;
#pragma unroll
  for (int off = 1; off < 64; off <<= 1) {
    int t = __shfl_up(incl, off);
    if (lane >= off) incl += t;
  }
  const int wtot = __shfl(incl, 63);
  int wb = 0;
  if (lane == 63) wb = atomicAdd(total, wtot);
  wb = __shfl(wb, 63);
  if (i < N_NODES) {
    const int e = wb + incl - d4;
    rowptr[i] = e;
    cursor[i] = e;
  }
}

// ---------- CSR fill ----------
__global__ void k_fill(const int* __restrict__ ei, const int* __restrict__ flag,
                       int* __restrict__ cursor, int* __restrict__ esrc) {
  int e = blockIdx.x * 256 + threadIdx.x;
  if (e < E_TOT) {
    int src, dst;
    if (e < N_EDGES) { src = ld_src(ei, *flag, e); dst = ld_dst(ei, *flag, e); }
    else             { src = dst = e - N_EDGES; }
    if ((unsigned)src < N_NODES && (unsigned)dst < N_NODES) {
      int pos = atomicAdd(&cursor[dst], 1);
      esrc[pos] = src;
    }
  }
}

// ---------- A-fragment loaders (8 contiguous k-elements -> bf16x8) ----------
__device__ __forceinline__ bf16x8 load8(const unsigned short* p) {
  uintx4 raw = *reinterpret_cast<const uintx4*>(p);
  return __builtin_bit_cast(bf16x8, raw);
}
__device__ __forceinline__ bf16x8 load8(const float* p) {
  floatx4 a = *reinterpret_cast<const floatx4*>(p);
  floatx4 b = *reinterpret_cast<const floatx4*>(p + 4);
  ushortx8 u;
#pragma unroll
  for (int i = 0; i < 4; ++i) { u[i] = f2bf(a[i]); u[4 + i] = f2bf(b[i]); }
  return __builtin_bit_cast(bf16x8, u);
}

// ---------- dual MFMA bf16 GEMM body: C{0,1}[M][NCOLS] = A[M][K] * BT{0,1}^T ----------
template <int K, int NCOLS, typename AT>
__device__ __forceinline__ void gemm_dual_body(
    int unit, int lane, const AT* __restrict__ A,
    const unsigned short* __restrict__ BT0, const unsigned short* __restrict__ BT1,
    unsigned short* __restrict__ C0, unsigned short* __restrict__ C1_, int M) {
  const int lo = lane & 15;   // m for A, n for B, col for C/D
  const int q  = lane >> 4;   // k-chunk quad
  const int r0 = unit * 32;
  if (r0 >= M) return;
  const bool two = (r0 + 16) < M;
  constexpr int KB = K / 32;

  bf16x8 afrag[2][KB];
#pragma unroll
  for (int kb = 0; kb < KB; ++kb)
    afrag[0][kb] = load8(A + (size_t)(r0 + lo) * K + kb * 32 + q * 8);
  if (two) {
#pragma unroll
    for (int kb = 0; kb < KB; ++kb)
      afrag[1][kb] = load8(A + (size_t)(r0 + 16 + lo) * K + kb * 32 + q * 8);
  }

#pragma unroll
  for (int o = 0; o < 2; ++o) {
    const unsigned short* BT = o ? BT1 : BT0;
    unsigned short* C = o ? C1_ : C0;
#pragma unroll
    for (int nt = 0; nt < NCOLS / 16; ++nt) {
      floatx4 acc0 = {0.f, 0.f, 0.f, 0.f};
      floatx4 acc1 = {0.f, 0.f, 0.f, 0.f};
      const unsigned short* bptr = BT + (size_t)(nt * 16 + lo) * K + q * 8;
#pragma unroll
      for (int kb = 0; kb < KB; ++kb) {
        bf16x8 b = load8(bptr + kb * 32);
        acc0 = __builtin_amdgcn_mfma_f32_16x16x32_bf16(afrag[0][kb], b, acc0, 0, 0, 0);
        if (two)
          acc1 = __builtin_amdgcn_mfma_f32_16x16x32_bf16(afrag[1][kb], b, acc1, 0, 0, 0);
      }
      // C/D layout: col = lane&15, row = (lane>>4)*4 + reg   [m89-verified]
#pragma unroll
      for (int r = 0; r < 4; ++r) {
        C[(size_t)(r0 + q * 4 + r) * NCOLS + nt * 16 + lo] = f2bf(acc0[r]);
        if (two)
          C[(size_t)(r0 + 16 + q * 4 + r) * NCOLS + nt * 16 + lo] = f2bf(acc1[r]);
      }
    }
  }
}

// ---------- fused GEMM1 + degree-count ----------
// GEMM blocks FIRST (0..GB1-1): resident early, run the whole dispatch.
// deg blocks (GB1..) stream through remaining wave slots — latency-bound
// atomic scatter overlaps the MFMA-bound GEMM.
__global__ __launch_bounds__(256) void k_gemm1_deg(
    const float* __restrict__ A,
    const unsigned short* __restrict__ BT0, const unsigned short* __restrict__ BT1,
    unsigned short* __restrict__ C0, unsigned short* __restrict__ C1_,
    const int* __restrict__ ei, const int* __restrict__ flag,
    int* __restrict__ deg) {
  if (blockIdx.x < GB1) {
    const int wave = threadIdx.x >> 6;
    const int lane = threadIdx.x & 63;
    gemm_dual_body<D_INF, C1, float>(blockIdx.x * 4 + wave, lane,
                                     A, BT0, BT1, C0, C1_, N_NODES);
    return;
  }
  const int e = (blockIdx.x - GB1) * 256 + threadIdx.x;
  if (e < E_TOT) {
    int dst = (e < N_EDGES) ? ld_dst(ei, *flag, e) : (e - N_EDGES);
    if ((unsigned)dst < N_NODES) atomicAdd(&deg[dst], 1);
  }
}

__global__ __launch_bounds__(256) void k_gemm2(
    const unsigned short* __restrict__ A,
    const unsigned short* __restrict__ BT0, const unsigned short* __restrict__ BT1,
    unsigned short* __restrict__ C0, unsigned short* __restrict__ C1_) {
  const int wave = threadIdx.x >> 6;
  const int lane = threadIdx.x & 63;
  gemm_dual_body<C1, HIDC, unsigned short>(blockIdx.x * 4 + wave, lane,
                                           A, BT0, BT1, C0, C1_, N_NODES);
}

// ---------- GAT layer 1 ----------
// One wave per dst; half h = lane>>5 owns alternating edge slots; lane w = lane&31
// owns channels w*8..w*8+7. Width-4 passes: ids one pass ahead, gathers two
// passes in flight. All gathers exactly guarded by deg (ids past deg are
// loaded but never dereferenced -> no arena zeroing needed).
// No softmax max-tracking (scores tiny; fmed3 clamp insurance).
// h1 may alias xr1 (own-row read-then-write).
__global__ __launch_bounds__(256) void k_gat1(
    const unsigned short* __restrict__ xl1, const unsigned short* __restrict__ xr1,
    const float* __restrict__ att1, const float* __restrict__ b1,
    const int* __restrict__ rowptr, const int* __restrict__ deg,
    const int* __restrict__ esrc, unsigned short* __restrict__ h1) {
  const int wave = threadIdx.x >> 6;
  const int lane = threadIdx.x & 63;
  const int dst = blockIdx.x * 4 + wave;
  if (dst >= N_NODES) return;
  const int h = lane >> 5;
  const int w = lane & 31;
  const int cb = w * 8;
  const unsigned short* __restrict__ xb = xl1 + cb;

  const int beg = rowptr[dst];
  const int n   = deg[dst];
  const int* __restrict__ ep = esrc + beg;

  floatx2 xr2v[4], att2v[4];
  {
    uintx4 r = *reinterpret_cast<const uintx4*>(xr1 + (size_t)dst * C1 + cb);
    floatx4 a0 = *reinterpret_cast<const floatx4*>(att1 + cb);
    floatx4 a1 = *reinterpret_cast<const floatx4*>(att1 + cb + 4);
#pragma unroll
    for (int j = 0; j < 4; ++j) xr2v[j] = bf2x2(r[j]);
    att2v[0] = floatx2{a0.x, a0.y} * LOG2E;
    att2v[1] = floatx2{a0.z, a0.w} * LOG2E;
    att2v[2] = floatx2{a1.x, a1.y} * LOG2E;
    att2v[3] = floatx2{a1.z, a1.w} * LOG2E;
  }

  float l = 0.f;
  floatx2 acc2[4] = {{0.f, 0.f}, {0.f, 0.f}, {0.f, 0.f}, {0.f, 0.f}};

  auto gath = [&](int a, int b) {
    const int s = h ? b : a;
    return *reinterpret_cast<const uintx4*>(xb + (size_t)s * C1);
  };
  auto process = [&](uintx4 cur, float keep) {
    floatx2 xs2[4];
    floatx2 v2 = {0.f, 0.f};
#pragma unroll
    for (int j = 0; j < 4; ++j) {
      xs2[j] = bf2x2(cur[j]);
      floatx2 s2 = xs2[j] + xr2v[j];
      floatx2 e2 = __builtin_elementwise_max(s2, s2 * NEG_SLOPE);   // leaky
      v2 = __builtin_elementwise_fma(e2, att2v[j], v2);
    }
    float v = v2.x + v2.y;
    v += __shfl_xor(v, 1);
    v += __shfl_xor(v, 2);            // 4-lane group = one head
    v = __builtin_amdgcn_fmed3f(v, -100.f, 100.f);
    const float p = __builtin_amdgcn_exp2f(v) * keep;
    l += p;
    const floatx2 p2 = {p, p};
#pragma unroll
    for (int j = 0; j < 4; ++j)
      acc2[j] = __builtin_elementwise_fma(p2, xs2[j], acc2[j]);
  };

  // prologue: pass0 ids+gathers, pass1 ids+gathers, pass2 ids
  intx4 ja = *reinterpret_cast<const intx4*>(ep);
  uintx4 g0 = {0u,0u,0u,0u}, g1 = {0u,0u,0u,0u};
  if (h     < n) g0 = gath(ja.x, ja.y);   // slots 0,1
  if (h + 2 < n) g1 = gath(ja.z, ja.w);   // slots 2,3
  intx4 jb4 = *reinterpret_cast<const intx4*>(ep + 4);
  uintx4 t0 = {0u,0u,0u,0u}, t1 = {0u,0u,0u,0u};
  if (n > 4) {
    const int r1 = n - 4;
    if (h     < r1) t0 = gath(jb4.x, jb4.y);
    if (h + 2 < r1) t1 = gath(jb4.z, jb4.w);
  }
  intx4 jn = *reinterpret_cast<const intx4*>(ep + 8);

  int base = 0;
  while (true) {
    const int rem = n - base;          // > 0
    uintx4 u0 = {0u,0u,0u,0u}, u1 = {0u,0u,0u,0u};
    if (rem > 8) {
      const int r2 = rem - 8;
      if (h     < r2) u0 = gath(jn.x, jn.y);
      if (h + 2 < r2) u1 = gath(jn.z, jn.w);
      jn = *reinterpret_cast<const intx4*>(ep + base + 12);
    }
    if (rem >= 4) {
      process(g0, 1.f);
      process(g1, 1.f);
    } else {
      process(g0, (h     < rem) ? 1.f : 0.f);
      process(g1, (h + 2 < rem) ? 1.f : 0.f);
    }
    if (rem <= 4) break;
    g0 = t0; g1 = t1; t0 = u0; t1 = u1;
    base += 4;
  }

  // merge the two halves (plain sums; no max bookkeeping)
  l += __shfl_xor(l, 32);
#pragma unroll
  for (int j = 0; j < 4; ++j) {
    acc2[j].x += __shfl_xor(acc2[j].x, 32);
    acc2[j].y += __shfl_xor(acc2[j].y, 32);
  }

  if (h == 0) {
    const float inv = 1.f / fmaxf(l, 1e-16f);
    ushortx8 ob;
#pragma unroll
    for (int j = 0; j < 4; ++j) {
      float z0 = acc2[j].x * inv + b1[cb + 2 * j];
      float z1 = acc2[j].y * inv + b1[cb + 2 * j + 1];
      z0 = z0 > 0.f ? z0 : (__expf(z0) - 1.f);   // ELU
      z1 = z1 > 0.f ? z1 : (__expf(z1) - 1.f);
      ob[2 * j]     = f2bf(z0);
      ob[2 * j + 1] = f2bf(z1);
    }
    *reinterpret_cast<ushortx8*>(h1 + (size_t)dst * C1 + cb) = ob;
  }
}

// ---------- GAT layer 2 (1 head, 32 ch) fused with final linear [32x16] ----------
__global__ __launch_bounds__(256) void k_gat2(
    const unsigned short* __restrict__ xl2, const unsigned short* __restrict__ xr2,
    const float* __restrict__ att2, const float* __restrict__ b2,
    const float* __restrict__ Wlin, const float* __restrict__ blin,
    const int* __restrict__ rowptr, const int* __restrict__ deg,
    const int* __restrict__ esrc, float* __restrict__ out) {
  __shared__ float sh[4][32];
  const int wave = threadIdx.x >> 6;
  const int lane = threadIdx.x & 63;
  const int dst = blockIdx.x * 4 + wave;
  if (dst >= N_NODES) return;
  const int o8 = lane >> 3;   // edge slot (8 edges in flight)
  const int w = lane & 7;     // channel group
  const int cb = w * 4;       // 4 ch = 2 bf16x2 pairs

  floatx2 xr2v[2], att2v[2];
  {
    uintx2 r = *reinterpret_cast<const uintx2*>(xr2 + (size_t)dst * HIDC + cb);
    floatx4 a = *reinterpret_cast<const floatx4*>(att2 + cb);
    xr2v[0] = bf2x2(r[0]);
    xr2v[1] = bf2x2(r[1]);
    att2v[0] = floatx2{a.x, a.y} * LOG2E;
    att2v[1] = floatx2{a.z, a.w} * LOG2E;
  }

  const int beg = rowptr[dst];
  const int n   = deg[dst];
  const int* __restrict__ ep = esrc + beg;

  float l = 0.f;
  floatx2 acc2[2] = {{0.f, 0.f}, {0.f, 0.f}};

  auto process = [&](uintx2 cur) {
    floatx2 xs2[2];
    floatx2 v2 = {0.f, 0.f};
#pragma unroll
    for (int j = 0; j < 2; ++j) {
      xs2[j] = bf2x2(cur[j]);
      floatx2 s2 = xs2[j] + xr2v[j];
      floatx2 e2 = __builtin_elementwise_max(s2, s2 * NEG_SLOPE);
      v2 = __builtin_elementwise_fma(e2, att2v[j], v2);
    }
    float v = v2.x + v2.y;
    v += __shfl_xor(v, 1);
    v += __shfl_xor(v, 2);
    v += __shfl_xor(v, 4);          // 8-lane group = full 32-ch head
    v = __builtin_amdgcn_fmed3f(v, -100.f, 100.f);
    const float p = __builtin_amdgcn_exp2f(v);
    l += p;
    const floatx2 p2 = {p, p};
#pragma unroll
    for (int j = 0; j < 2; ++j)
      acc2[j] = __builtin_elementwise_fma(p2, xs2[j], acc2[j]);
  };

  uintx2 bufa = {0u, 0u}, bufb = {0u, 0u};
  if (o8 < n)
    bufa = *reinterpret_cast<const uintx2*>(xl2 + (size_t)ep[o8] * HIDC + cb);
  if (o8 + 8 < n)
    bufb = *reinterpret_cast<const uintx2*>(xl2 + (size_t)ep[o8 + 8] * HIDC + cb);
  int i = o8;
  while (i < n) {
    process(bufa);
    if (i + 16 < n)
      bufa = *reinterpret_cast<const uintx2*>(xl2 + (size_t)ep[i + 16] * HIDC + cb);
    i += 8;
    if (i >= n) break;
    process(bufb);
    if (i + 16 < n)
      bufb = *reinterpret_cast<const uintx2*>(xl2 + (size_t)ep[i + 16] * HIDC + cb);
    i += 8;
  }

  // merge 8 octets (plain sums)
#pragma unroll
  for (int k = 8; k < 64; k <<= 1) {
    l += __shfl_xor(l, k);
#pragma unroll
    for (int j = 0; j < 2; ++j) {
      acc2[j].x += __shfl_xor(acc2[j].x, k);
      acc2[j].y += __shfl_xor(acc2[j].y, k);
    }
  }

  if (o8 == 0) {
    const float inv = 1.f / fmaxf(l, 1e-16f);
#pragma unroll
    for (int j = 0; j < 2; ++j) {
      float z0 = acc2[j].x * inv + b2[cb + 2 * j];
      float z1 = acc2[j].y * inv + b2[cb + 2 * j + 1];
      z0 = z0 > 0.f ? z0 : (__expf(z0) - 1.f);   // ELU
      z1 = z1 > 0.f ? z1 : (__expf(z1) - 1.f);
      sh[wave][cb + 2 * j]     = z0;
      sh[wave][cb + 2 * j + 1] = z1;
    }
  }
  if (lane < OUTC) {
    float o = blin[lane];
#pragma unroll
    for (int k = 0; k < 32; ++k)
      o = fmaf(sh[wave][k], Wlin[k * OUTC + lane], o);
    out[(size_t)dst * OUTC + lane] = o;
  }
}

static inline int cdiv(int a, int b) { return (a + b - 1) / b; }

extern "C" void kernel_launch(void* const* d_in, const int* in_sizes, int n_in,
                              void* d_out, int out_size, void* d_ws, size_t ws_size,
                              hipStream_t stream) {
  const float* x    = (const float*)d_in[0];
  const int*   ei   = (const int*)d_in[1];
  const float* W1l  = (const float*)d_in[2];
  const float* W1r  = (const float*)d_in[3];
  const float* att1 = (const float*)d_in[4];
  const float* b1   = (const float*)d_in[5];
  const float* W2l  = (const float*)d_in[6];
  const float* W2r  = (const float*)d_in[7];
  const float* att2 = (const float*)d_in[8];
  const float* b2   = (const float*)d_in[9];
  const float* Wlin = (const float*)d_in[10];
  const float* blin = (const float*)d_in[11];
  float* out = (float*)d_out;

  char* w = (char*)d_ws;
  auto alloc = [&](size_t bytes) -> char* {
    char* p = w;
    w += (bytes + 255) & ~(size_t)255;
    return p;
  };
  // region A: xl1 (bf16), later reused for xl2+xr2
  char* regionA = alloc((size_t)N_NODES * C1 * 2);          // 25.6 MB
  unsigned short* xl1 = (unsigned short*)regionA;
  unsigned short* xl2 = (unsigned short*)regionA;                           // 3.2 MB
  unsigned short* xr2 = (unsigned short*)(regionA + (size_t)N_NODES * HIDC * 2 + 256);
  // region B: xr1 aliased with h1 (safe: per-wave own-row read-then-write)
  unsigned short* xr1 = (unsigned short*)alloc((size_t)N_NODES * C1 * 2);   // 25.6 MB
  unsigned short* h1  = xr1;
  unsigned short* W1lT = (unsigned short*)alloc((size_t)D_INF * C1 * 2);
  unsigned short* W1rT = (unsigned short*)alloc((size_t)D_INF * C1 * 2);
  unsigned short* W2lT = (unsigned short*)alloc((size_t)C1 * HIDC * 2);
  unsigned short* W2rT = (unsigned short*)alloc((size_t)C1 * HIDC * 2);
  int* rowptr = (int*)alloc((size_t)N_NODES * 4);
  int* cursor = (int*)alloc((size_t)N_NODES * 4);
  int* deg    = (int*)alloc((size_t)N_NODES * 4);
  int* esrc   = (int*)alloc((size_t)ESRC_CAP * 4);          // 2.4 MB
  int* flag   = (int*)alloc(4);
  int* total  = (int*)alloc(4);

  k_prep<<<PREP_GRID, 256, 0, stream>>>(ei, W1l, W1r, W2l, W2r,
                                        W1lT, W1rT, W2lT, W2rT,
                                        deg, total, flag);

  // GEMM1 (blocks first) + degree count overlapped in one dispatch
  k_gemm1_deg<<<GB1 + DEGB, 256, 0, stream>>>(x, W1lT, W1rT, xl1, xr1,
                                              ei, flag, deg);

  k_alloc<<<cdiv(N_NODES, 256), 256, 0, stream>>>(deg, rowptr, cursor, total);
  k_fill<<<FILLB, 256, 0, stream>>>(ei, flag, cursor, esrc);

  k_gat1<<<cdiv(N_NODES, 4), 256, 0, stream>>>(xl1, xr1, att1, b1,
                                               rowptr, deg, esrc, h1);

  // GEMM2: [50000,256] x ([256,32] x2) -> xl2, xr2
  k_gemm2<<<cdiv(cdiv(N_NODES, 32), 4), 256, 0, stream>>>(h1, W2lT, W2rT, xl2, xr2);

  k_gat2<<<cdiv(N_NODES, 4), 256, 0, stream>>>(xl2, xr2, att2, b2, Wlin, blin,
                                               rowptr, deg, esrc, out);
}

// Round 4
// 270.601 us; speedup vs baseline: 1.1460x; 1.0081x over previous
//
#include <hip/hip_runtime.h>
#include <cstdint>
#include <cstddef>

#define N_NODES 50000
#define N_EDGES 400000
#define E_TOT   (N_EDGES + N_NODES)   // with self-loops
#define D_INF   128
#define C1      256                   // 8 heads * 32
#define HIDC    32
#define OUTC    16
#define NEG_SLOPE 0.2f
#define LOG2E   1.44269504088896340736f

// esrc arena: per-node segment rounded up to 4 ints; ids past deg[dst]
// are never read (gat kernels guard by deg).
#define ESRC_CAP (E_TOT + 3 * N_NODES + 16)     // 600016

#define TB_W   ((2 * D_INF * C1 + 2 * C1 * HIDC + 255) / 256)   // 320: transposes
#define DEGB   ((E_TOT + 255) / 256)            // 1758 deg blocks
#define FILLB  ((E_TOT + 255) / 256)            // 1758 fill blocks

#define UNITS1 ((N_NODES + 31) / 32)            // 1563 row-units of 32
#define GB1S   ((2 * UNITS1 + 3) / 4)           // 782 GEMM1 blocks (split outputs)
#define GB2S   ((2 * UNITS1 + 3) / 4)           // 782 GEMM2 blocks

typedef __bf16 bf16x8 __attribute__((ext_vector_type(8)));
typedef float  floatx4 __attribute__((ext_vector_type(4)));
typedef float  floatx2 __attribute__((ext_vector_type(2)));
typedef unsigned int uintx4 __attribute__((ext_vector_type(4)));
typedef unsigned int uintx2 __attribute__((ext_vector_type(2)));
typedef unsigned short ushortx8 __attribute__((ext_vector_type(8)));
typedef unsigned short ushortx4 __attribute__((ext_vector_type(4)));

__device__ __forceinline__ unsigned short f2bf(float f) {
  unsigned int u = __builtin_bit_cast(unsigned int, f);
  u += 0x7FFFu + ((u >> 16) & 1u);   // RNE (finite values)
  return (unsigned short)(u >> 16);
}
__device__ __forceinline__ float bf2f(unsigned short u) {
  return __builtin_bit_cast(float, (unsigned int)u << 16);
}
// packed bf16x2 word -> float2 (channels 2j, 2j+1)
__device__ __forceinline__ floatx2 bf2x2(unsigned int u) {
  floatx2 r;
  r.x = __builtin_bit_cast(float, u << 16);
  r.y = __builtin_bit_cast(float, u & 0xffff0000u);
  return r;
}

__device__ __forceinline__ int ld_src(const int* ei, int f, int e) {
  return f ? ei[2 * e] : ei[e];
}
__device__ __forceinline__ int ld_dst(const int* ei, int f, int e) {
  return f ? ei[2 * (N_EDGES + e)] : ei[N_EDGES + e];
}

// ---------- edge_index word-width autodetect ----------
__global__ void k_detect(const int* __restrict__ ei, int* __restrict__ flag) {
  __shared__ int s;
  if (threadIdx.x == 0) s = 0;
  __syncthreads();
  atomicOr(&s, ei[2 * threadIdx.x + 1]);
  __syncthreads();
  if (threadIdx.x == 0) *flag = (s == 0) ? 1 : 0;   // 1 = int64
}

// ---------- prep: degree count (long pole, first) + 4 weight transposes ----------
__global__ __launch_bounds__(256) void k_prep(
    const int* __restrict__ ei, const int* __restrict__ flag,
    const float* __restrict__ W1l, const float* __restrict__ W1r,
    const float* __restrict__ W2l, const float* __restrict__ W2r,
    unsigned short* __restrict__ W1lT, unsigned short* __restrict__ W1rT,
    unsigned short* __restrict__ W2lT, unsigned short* __restrict__ W2rT,
    int* __restrict__ deg) {
  const int bid = blockIdx.x;
  const int tid = threadIdx.x;
  if (bid < DEGB) {
    const int e = bid * 256 + tid;
    if (e < E_TOT) {
      int dst = (e < N_EDGES) ? ld_dst(ei, *flag, e) : (e - N_EDGES);
      if ((unsigned)dst < N_NODES) atomicAdd(&deg[dst], 1);
    }
    return;
  }
  int idx = (bid - DEGB) * 256 + tid;
  if (idx < D_INF * C1) {                       // W1l: [128][256] -> T
    const int r = idx >> 8, c = idx & 255;
    W1lT[c * D_INF + r] = f2bf(W1l[idx]);
  } else if (idx < 2 * D_INF * C1) {            // W1r
    idx -= D_INF * C1;
    const int r = idx >> 8, c = idx & 255;
    W1rT[c * D_INF + r] = f2bf(W1r[idx]);
  } else if (idx < 2 * D_INF * C1 + C1 * HIDC) { // W2l: [256][32] -> T
    idx -= 2 * D_INF * C1;
    const int r = idx >> 5, c = idx & 31;
    W2lT[c * C1 + r] = f2bf(W2l[idx]);
  } else if (idx < 2 * (D_INF * C1 + C1 * HIDC)) { // W2r
    idx -= 2 * D_INF * C1 + C1 * HIDC;
    const int r = idx >> 5, c = idx & 31;
    W2rT[c * C1 + r] = f2bf(W2r[idx]);
  }
}

// ---------- segment allocation: per-wave prefix + one atomic per wave ----------
__global__ __launch_bounds__(256) void k_alloc(
    const int* __restrict__ deg, int* __restrict__ rowptr,
    int* __restrict__ cursor, int* __restrict__ total) {
  const int i = blockIdx.x * 256 + threadIdx.x;
  const int lane = threadIdx.x & 63;
  const int d  = (i < N_NODES) ? deg[i] : 0;
  const int d4 = (d + 3) & ~3;
  int incl = d4;
#pragma unroll
  for (int off = 1; off < 64; off <<= 1) {
    int t = __shfl_up(incl, off);
    if (lane >= off) incl += t;
  }
  const int wtot = __shfl(incl, 63);
  int wb = 0;
  if (lane == 63) wb = atomicAdd(total, wtot);
  wb = __shfl(wb, 63);
  if (i < N_NODES) {
    const int e = wb + incl - d4;
    rowptr[i] = e;
    cursor[i] = e;
  }
}

// ---------- A-fragment loaders (8 contiguous k-elements -> bf16x8) ----------
__device__ __forceinline__ bf16x8 load8(const unsigned short* p) {
  uintx4 raw = *reinterpret_cast<const uintx4*>(p);
  return __builtin_bit_cast(bf16x8, raw);
}
__device__ __forceinline__ bf16x8 load8(const float* p) {
  floatx4 a = *reinterpret_cast<const floatx4*>(p);
  floatx4 b = *reinterpret_cast<const floatx4*>(p + 4);
  ushortx8 u;
#pragma unroll
  for (int i = 0; i < 4; ++i) { u[i] = f2bf(a[i]); u[4 + i] = f2bf(b[i]); }
  return __builtin_bit_cast(bf16x8, u);
}

// ---------- single-output MFMA bf16 GEMM body: C[M][NCOLS] = A[M][K] * BT^T ----------
template <int K, int NCOLS, typename AT>
__device__ __forceinline__ void gemm_body(
    int unit, int lane, const AT* __restrict__ A,
    const unsigned short* __restrict__ BT,
    unsigned short* __restrict__ C, int M) {
  const int lo = lane & 15;   // m for A, n for B, col for C/D
  const int q  = lane >> 4;   // k-chunk quad
  const int r0 = unit * 32;
  if (r0 >= M) return;
  const bool two = (r0 + 16) < M;
  constexpr int KB = K / 32;

  bf16x8 afrag[2][KB];
#pragma unroll
  for (int kb = 0; kb < KB; ++kb)
    afrag[0][kb] = load8(A + (size_t)(r0 + lo) * K + kb * 32 + q * 8);
  if (two) {
#pragma unroll
    for (int kb = 0; kb < KB; ++kb)
      afrag[1][kb] = load8(A + (size_t)(r0 + 16 + lo) * K + kb * 32 + q * 8);
  }

#pragma unroll
  for (int nt = 0; nt < NCOLS / 16; ++nt) {
    floatx4 acc0 = {0.f, 0.f, 0.f, 0.f};
    floatx4 acc1 = {0.f, 0.f, 0.f, 0.f};
    const unsigned short* bptr = BT + (size_t)(nt * 16 + lo) * K + q * 8;
#pragma unroll
    for (int kb = 0; kb < KB; ++kb) {
      bf16x8 b = load8(bptr + kb * 32);
      acc0 = __builtin_amdgcn_mfma_f32_16x16x32_bf16(afrag[0][kb], b, acc0, 0, 0, 0);
      if (two)
        acc1 = __builtin_amdgcn_mfma_f32_16x16x32_bf16(afrag[1][kb], b, acc1, 0, 0, 0);
    }
    // C/D layout: col = lane&15, row = (lane>>4)*4 + reg   [m89-verified]
#pragma unroll
    for (int r = 0; r < 4; ++r) {
      C[(size_t)(r0 + q * 4 + r) * NCOLS + nt * 16 + lo] = f2bf(acc0[r]);
      if (two)
        C[(size_t)(r0 + 16 + q * 4 + r) * NCOLS + nt * 16 + lo] = f2bf(acc1[r]);
    }
  }
}

// ---------- fused GEMM1 (split outputs; blocks first) + CSR fill (streams after) ----------
__global__ __launch_bounds__(256) void k_gemm1_fill(
    const float* __restrict__ A,
    const unsigned short* __restrict__ BT0, const unsigned short* __restrict__ BT1,
    unsigned short* __restrict__ C0, unsigned short* __restrict__ C1_,
    const int* __restrict__ ei, const int* __restrict__ flag,
    int* __restrict__ cursor, int* __restrict__ esrc) {
  if (blockIdx.x < GB1S) {
    const int wave = threadIdx.x >> 6;
    const int lane = threadIdx.x & 63;
    const int unit = blockIdx.x * 4 + wave;       // 0..3127
    const int o = (unit >= UNITS1) ? 1 : 0;       // which output matrix
    const int ru = unit - o * UNITS1;             // row-unit within output
    gemm_body<D_INF, C1, float>(ru, lane, A, o ? BT1 : BT0, o ? C1_ : C0, N_NODES);
    return;
  }
  const int e = (blockIdx.x - GB1S) * 256 + threadIdx.x;
  if (e < E_TOT) {
    int src, dst;
    if (e < N_EDGES) { src = ld_src(ei, *flag, e); dst = ld_dst(ei, *flag, e); }
    else             { src = dst = e - N_EDGES; }
    if ((unsigned)src < N_NODES && (unsigned)dst < N_NODES) {
      int pos = atomicAdd(&cursor[dst], 1);
      esrc[pos] = src;
    }
  }
}

// ---------- GEMM2 (split outputs) ----------
__global__ __launch_bounds__(256) void k_gemm2(
    const unsigned short* __restrict__ A,
    const unsigned short* __restrict__ BT0, const unsigned short* __restrict__ BT1,
    unsigned short* __restrict__ C0, unsigned short* __restrict__ C1_) {
  const int wave = threadIdx.x >> 6;
  const int lane = threadIdx.x & 63;
  const int unit = blockIdx.x * 4 + wave;
  const int o = (unit >= UNITS1) ? 1 : 0;
  const int ru = unit - o * UNITS1;
  gemm_body<C1, HIDC, unsigned short>(ru, lane, A, o ? BT1 : BT0, o ? C1_ : C0, N_NODES);
}

// ---------- GAT layer 1 (round-1 proven structure) ----------
// One wave per dst (4 per block); half h = lane>>5 processes alternating edges;
// lane w = lane&31 owns channels w*8..w*8+7. 2-deep ping-pong gather prefetch.
// No softmax max-tracking (scores tiny; clamp insurance). log2e folded into att.
// h1 may alias xr1 (own-row read-then-write).
__global__ __launch_bounds__(256) void k_gat1(
    const unsigned short* __restrict__ xl1, const unsigned short* __restrict__ xr1,
    const float* __restrict__ att1, const float* __restrict__ b1,
    const int* __restrict__ rowptr, const int* __restrict__ deg,
    const int* __restrict__ esrc, unsigned short* __restrict__ h1) {
  const int wave = threadIdx.x >> 6;
  const int lane = threadIdx.x & 63;
  const int dst = blockIdx.x * 4 + wave;
  if (dst >= N_NODES) return;
  const int h = lane >> 5;
  const int w = lane & 31;
  const int cb = w * 8;

  floatx2 xr2v[4], att2v[4];
  {
    uintx4 r = *reinterpret_cast<const uintx4*>(xr1 + (size_t)dst * C1 + cb);
    floatx4 a0 = *reinterpret_cast<const floatx4*>(att1 + cb);
    floatx4 a1 = *reinterpret_cast<const floatx4*>(att1 + cb + 4);
#pragma unroll
    for (int j = 0; j < 4; ++j) xr2v[j] = bf2x2(r[j]);
    att2v[0] = floatx2{a0.x, a0.y} * LOG2E;
    att2v[1] = floatx2{a0.z, a0.w} * LOG2E;
    att2v[2] = floatx2{a1.x, a1.y} * LOG2E;
    att2v[3] = floatx2{a1.z, a1.w} * LOG2E;
  }

  const int beg = rowptr[dst];
  const int n   = deg[dst];
  const int* __restrict__ ep = esrc + beg;

  float l = 0.f;
  floatx2 acc2[4] = {{0.f, 0.f}, {0.f, 0.f}, {0.f, 0.f}, {0.f, 0.f}};

  auto process = [&](uintx4 cur) {
    floatx2 xs2[4];
    floatx2 v2 = {0.f, 0.f};
#pragma unroll
    for (int j = 0; j < 4; ++j) {
      xs2[j] = bf2x2(cur[j]);
      floatx2 s2 = xs2[j] + xr2v[j];
      floatx2 e2 = __builtin_elementwise_max(s2, s2 * NEG_SLOPE);   // leaky
      v2 = __builtin_elementwise_fma(e2, att2v[j], v2);
    }
    float v = v2.x + v2.y;
    v += __shfl_xor(v, 1);
    v += __shfl_xor(v, 2);          // 4-lane group = one head
    v = fminf(fmaxf(v, -100.f), 100.f);
    const float p = __builtin_amdgcn_exp2f(v);   // exp(score): log2e in att
    l += p;
    const floatx2 p2 = {p, p};
#pragma unroll
    for (int j = 0; j < 4; ++j)
      acc2[j] = __builtin_elementwise_fma(p2, xs2[j], acc2[j]);
  };

  // ping-pong double-buffered gather, 2 iterations of prefetch depth
  uintx4 bufa = {0u, 0u, 0u, 0u}, bufb = {0u, 0u, 0u, 0u};
  if (h < n)
    bufa = *reinterpret_cast<const uintx4*>(xl1 + (size_t)ep[h] * C1 + cb);
  if (h + 2 < n)
    bufb = *reinterpret_cast<const uintx4*>(xl1 + (size_t)ep[h + 2] * C1 + cb);
  int i = h;
  while (i < n) {
    process(bufa);
    if (i + 4 < n)
      bufa = *reinterpret_cast<const uintx4*>(xl1 + (size_t)ep[i + 4] * C1 + cb);
    i += 2;
    if (i >= n) break;
    process(bufb);
    if (i + 4 < n)
      bufb = *reinterpret_cast<const uintx4*>(xl1 + (size_t)ep[i + 4] * C1 + cb);
    i += 2;
  }

  // merge the two halves (plain sums; no max bookkeeping)
  l += __shfl_xor(l, 32);
#pragma unroll
  for (int j = 0; j < 4; ++j) {
    acc2[j].x += __shfl_xor(acc2[j].x, 32);
    acc2[j].y += __shfl_xor(acc2[j].y, 32);
  }

  if (h == 0) {
    const float inv = 1.f / fmaxf(l, 1e-16f);
    ushortx8 ob;
#pragma unroll
    for (int j = 0; j < 4; ++j) {
      float z0 = acc2[j].x * inv + b1[cb + 2 * j];
      float z1 = acc2[j].y * inv + b1[cb + 2 * j + 1];
      z0 = z0 > 0.f ? z0 : (__expf(z0) - 1.f);   // ELU
      z1 = z1 > 0.f ? z1 : (__expf(z1) - 1.f);
      ob[2 * j]     = f2bf(z0);
      ob[2 * j + 1] = f2bf(z1);
    }
    *reinterpret_cast<ushortx8*>(h1 + (size_t)dst * C1 + cb) = ob;
  }
}

// ---------- GAT layer 2 (1 head, 32 ch) fused with final linear [32x16] ----------
__global__ __launch_bounds__(256) void k_gat2(
    const unsigned short* __restrict__ xl2, const unsigned short* __restrict__ xr2,
    const float* __restrict__ att2, const float* __restrict__ b2,
    const float* __restrict__ Wlin, const float* __restrict__ blin,
    const int* __restrict__ rowptr, const int* __restrict__ deg,
    const int* __restrict__ esrc, float* __restrict__ out) {
  __shared__ float sh[4][32];
  const int wave = threadIdx.x >> 6;
  const int lane = threadIdx.x & 63;
  const int dst = blockIdx.x * 4 + wave;
  if (dst >= N_NODES) return;
  const int o8 = lane >> 3;   // edge slot (8 edges in flight)
  const int w = lane & 7;     // channel group
  const int cb = w * 4;       // 4 ch = 2 bf16x2 pairs

  floatx2 xr2v[2], att2v[2];
  {
    uintx2 r = *reinterpret_cast<const uintx2*>(xr2 + (size_t)dst * HIDC + cb);
    floatx4 a = *reinterpret_cast<const floatx4*>(att2 + cb);
    xr2v[0] = bf2x2(r[0]);
    xr2v[1] = bf2x2(r[1]);
    att2v[0] = floatx2{a.x, a.y} * LOG2E;
    att2v[1] = floatx2{a.z, a.w} * LOG2E;
  }

  const int beg = rowptr[dst];
  const int n   = deg[dst];
  const int* __restrict__ ep = esrc + beg;

  float l = 0.f;
  floatx2 acc2[2] = {{0.f, 0.f}, {0.f, 0.f}};

  auto process = [&](uintx2 cur) {
    floatx2 xs2[2];
    floatx2 v2 = {0.f, 0.f};
#pragma unroll
    for (int j = 0; j < 2; ++j) {
      xs2[j] = bf2x2(cur[j]);
      floatx2 s2 = xs2[j] + xr2v[j];
      floatx2 e2 = __builtin_elementwise_max(s2, s2 * NEG_SLOPE);
      v2 = __builtin_elementwise_fma(e2, att2v[j], v2);
    }
    float v = v2.x + v2.y;
    v += __shfl_xor(v, 1);
    v += __shfl_xor(v, 2);
    v += __shfl_xor(v, 4);          // 8-lane group = full 32-ch head
    v = fminf(fmaxf(v, -100.f), 100.f);
    const float p = __builtin_amdgcn_exp2f(v);
    l += p;
    const floatx2 p2 = {p, p};
#pragma unroll
    for (int j = 0; j < 2; ++j)
      acc2[j] = __builtin_elementwise_fma(p2, xs2[j], acc2[j]);
  };

  uintx2 bufa = {0u, 0u}, bufb = {0u, 0u};
  if (o8 < n)
    bufa = *reinterpret_cast<const uintx2*>(xl2 + (size_t)ep[o8] * HIDC + cb);
  if (o8 + 8 < n)
    bufb = *reinterpret_cast<const uintx2*>(xl2 + (size_t)ep[o8 + 8] * HIDC + cb);
  int i = o8;
  while (i < n) {
    process(bufa);
    if (i + 16 < n)
      bufa = *reinterpret_cast<const uintx2*>(xl2 + (size_t)ep[i + 16] * HIDC + cb);
    i += 8;
    if (i >= n) break;
    process(bufb);
    if (i + 16 < n)
      bufb = *reinterpret_cast<const uintx2*>(xl2 + (size_t)ep[i + 16] * HIDC + cb);
    i += 8;
  }

  // merge 8 octets (plain sums)
#pragma unroll
  for (int k = 8; k < 64; k <<= 1) {
    l += __shfl_xor(l, k);
#pragma unroll
    for (int j = 0; j < 2; ++j) {
      acc2[j].x += __shfl_xor(acc2[j].x, k);
      acc2[j].y += __shfl_xor(acc2[j].y, k);
    }
  }

  if (o8 == 0) {
    const float inv = 1.f / fmaxf(l, 1e-16f);
#pragma unroll
    for (int j = 0; j < 2; ++j) {
      float z0 = acc2[j].x * inv + b2[cb + 2 * j];
      float z1 = acc2[j].y * inv + b2[cb + 2 * j + 1];
      z0 = z0 > 0.f ? z0 : (__expf(z0) - 1.f);   // ELU
      z1 = z1 > 0.f ? z1 : (__expf(z1) - 1.f);
      sh[wave][cb + 2 * j]     = z0;
      sh[wave][cb + 2 * j + 1] = z1;
    }
  }
  if (lane < OUTC) {
    float o = blin[lane];
#pragma unroll
    for (int k = 0; k < 32; ++k)
      o = fmaf(sh[wave][k], Wlin[k * OUTC + lane], o);
    out[(size_t)dst * OUTC + lane] = o;
  }
}

static inline int cdiv(int a, int b) { return (a + b - 1) / b; }

extern "C" void kernel_launch(void* const* d_in, const int* in_sizes, int n_in,
                              void* d_out, int out_size, void* d_ws, size_t ws_size,
                              hipStream_t stream) {
  const float* x    = (const float*)d_in[0];
  const int*   ei   = (const int*)d_in[1];
  const float* W1l  = (const float*)d_in[2];
  const float* W1r  = (const float*)d_in[3];
  const float* att1 = (const float*)d_in[4];
  const float* b1   = (const float*)d_in[5];
  const float* W2l  = (const float*)d_in[6];
  const float* W2r  = (const float*)d_in[7];
  const float* att2 = (const float*)d_in[8];
  const float* b2   = (const float*)d_in[9];
  const float* Wlin = (const float*)d_in[10];
  const float* blin = (const float*)d_in[11];
  float* out = (float*)d_out;

  char* w = (char*)d_ws;
  auto alloc = [&](size_t bytes) -> char* {
    char* p = w;
    w += (bytes + 255) & ~(size_t)255;
    return p;
  };
  // region A: xl1 (bf16), later reused for xl2+xr2
  char* regionA = alloc((size_t)N_NODES * C1 * 2);          // 25.6 MB
  unsigned short* xl1 = (unsigned short*)regionA;
  unsigned short* xl2 = (unsigned short*)regionA;                           // 3.2 MB
  unsigned short* xr2 = (unsigned short*)(regionA + (size_t)N_NODES * HIDC * 2 + 256);
  // region B: xr1 aliased with h1 (safe: per-wave own-row read-then-write)
  unsigned short* xr1 = (unsigned short*)alloc((size_t)N_NODES * C1 * 2);   // 25.6 MB
  unsigned short* h1  = xr1;
  unsigned short* W1lT = (unsigned short*)alloc((size_t)D_INF * C1 * 2);
  unsigned short* W1rT = (unsigned short*)alloc((size_t)D_INF * C1 * 2);
  unsigned short* W2lT = (unsigned short*)alloc((size_t)C1 * HIDC * 2);
  unsigned short* W2rT = (unsigned short*)alloc((size_t)C1 * HIDC * 2);
  int* rowptr = (int*)alloc((size_t)N_NODES * 4);
  int* cursor = (int*)alloc((size_t)N_NODES * 4);
  int* deg    = (int*)alloc((size_t)(N_NODES + 1) * 4);     // deg + total (contiguous)
  int* total  = deg + N_NODES;
  int* esrc   = (int*)alloc((size_t)ESRC_CAP * 4);          // 2.4 MB
  int* flag   = (int*)alloc(4);

  hipMemsetAsync(deg, 0, (size_t)(N_NODES + 1) * 4, stream);   // deg + total
  k_detect<<<1, 64, 0, stream>>>(ei, flag);

  // degree count (long pole first) + weight transposes, one dispatch
  k_prep<<<DEGB + TB_W, 256, 0, stream>>>(ei, flag, W1l, W1r, W2l, W2r,
                                          W1lT, W1rT, W2lT, W2rT, deg);

  k_alloc<<<cdiv(N_NODES, 256), 256, 0, stream>>>(deg, rowptr, cursor, total);

  // GEMM1 (split-output blocks first: 782 = 3 blocks/CU) + CSR fill streamed after
  k_gemm1_fill<<<GB1S + FILLB, 256, 0, stream>>>(x, W1lT, W1rT, xl1, xr1,
                                                 ei, flag, cursor, esrc);

  k_gat1<<<cdiv(N_NODES, 4), 256, 0, stream>>>(xl1, xr1, att1, b1,
                                               rowptr, deg, esrc, h1);

  // GEMM2 (split outputs): [50000,256] x ([256,32] x2) -> xl2, xr2
  k_gemm2<<<GB2S, 256, 0, stream>>>(h1, W2lT, W2rT, xl2, xr2);

  k_gat2<<<cdiv(N_NODES, 4), 256, 0, stream>>>(xl2, xr2, att2, b2, Wlin, blin,
                                               rowptr, deg, esrc, out);
}